// Round 12
// baseline (251.300 us; speedup 1.0000x reference)
//
#include <hip/hip_runtime.h>
#include <hip/hip_bf16.h>

#define DHW (16 * 16 * 30)   // 7680 voxels per channel
#define NWCOL 7680           // hw columns = 120 f * 64 c
#define KTOT 30720           // hw rows
#define KSPLIT 120
#define KCH (KTOT / KSPLIT)  // 256 rows per block
#define NBLK (15 * KSPLIT)   // 1800 K2 blocks
// ln(1024)/39
#define LN1024_OVER_39 0.17773004629742187f

// ---------------------------------------------------------------------------
// K1 v3: conv chain, LDS-issue-minimized. One 256-thread block per (b,zi,yi).
// Weights read DIRECTLY from global (L2-hot: cw1 128 KB reused by all 512
// blocks) -> VMEM pipe; activations in LDS (28 KB) -> 1 LDS b64 per 8 FMA.
// 3 syncs total (vs 12 in the staged version measured at 31 us = LDS-bound).
// Writes fvecT[k][b], k = ((ch*8+zi)*8+yi)*15 + w   (torch flatten order)
// ---------------------------------------------------------------------------
__global__ __launch_bounds__(256) void k1_conv(
    const float* __restrict__ feat0,
    const float* __restrict__ cw1, const float* __restrict__ cb1,
    const float* __restrict__ cw2, const float* __restrict__ cb2,
    const float* __restrict__ cw3, const float* __restrict__ cb3,
    float* __restrict__ fvecT)
{
    const int yi = blockIdx.x;   // 0..7
    const int zi = blockIdx.y;   // 0..7
    const int b  = blockIdx.z;   // 0..7
    const int t  = threadIdx.x;  // 0..255

    __shared__ float sIn[256][16];  // [c][w] 16 KB
    __shared__ float sH1[128][16];  // 8 KB
    __shared__ float sH2[64][16];   // 4 KB   (28 KB total)

    // ---- load input voxels: feat0[b, c, 2zi, 2yi, 2w], w = 0..14 ----
    {
        const int w  = t & 15;
        const int cg = t >> 4;  // 0..15
        const float* base = feat0 + (size_t)b * 256 * DHW
                            + (2 * zi) * (16 * 30) + (2 * yi) * 30 + 2 * w;
        #pragma unroll
        for (int c0 = 0; c0 < 256; c0 += 16) {
            const int c = c0 + cg;
            sIn[c][w] = (w < 15) ? base[(size_t)c * DHW] : 0.f;
        }
    }
    __syncthreads();

    // ---- conv1: 256 -> 128, relu.  thread = (oq = t&31 -> 4 o's,
    //      wh = t>>5 -> 2 w's).  Per c: 1 global b128 (wv) + 1 LDS b64 (xi)
    //      + 8 FMA.
    {
        const int o0 = 4 * (t & 31), w0 = 2 * (t >> 5);
        const float4 bv = *(const float4*)&cb1[o0];
        float acc0[4] = {bv.x, bv.y, bv.z, bv.w};
        float acc1[4] = {bv.x, bv.y, bv.z, bv.w};
        #pragma unroll 8
        for (int c = 0; c < 256; ++c) {
            const float4 wv = *(const float4*)&cw1[c * 128 + o0];
            const float2 xi = *(const float2*)&sIn[c][w0];
            acc0[0] += xi.x * wv.x; acc1[0] += xi.y * wv.x;
            acc0[1] += xi.x * wv.y; acc1[1] += xi.y * wv.y;
            acc0[2] += xi.x * wv.z; acc1[2] += xi.y * wv.z;
            acc0[3] += xi.x * wv.w; acc1[3] += xi.y * wv.w;
        }
        #pragma unroll
        for (int j = 0; j < 4; ++j) {
            sH1[o0 + j][w0]     = fmaxf(acc0[j], 0.f);
            sH1[o0 + j][w0 + 1] = fmaxf(acc1[j], 0.f);
        }
    }
    __syncthreads();

    // ---- conv2: 128 -> 64, relu.  thread = (op = t&31 -> 2 o's,
    //      wh = t>>5 -> 2 w's). Per c: 1 global b64 + 1 LDS b64 + 4 FMA.
    {
        const int o0 = 2 * (t & 31), w0 = 2 * (t >> 5);
        const float2 bv = *(const float2*)&cb2[o0];
        float acc0[2] = {bv.x, bv.y};
        float acc1[2] = {bv.x, bv.y};
        #pragma unroll 8
        for (int c = 0; c < 128; ++c) {
            const float2 wv = *(const float2*)&cw2[c * 64 + o0];
            const float2 xi = *(const float2*)&sH1[c][w0];
            acc0[0] += xi.x * wv.x; acc1[0] += xi.y * wv.x;
            acc0[1] += xi.x * wv.y; acc1[1] += xi.y * wv.y;
        }
        sH2[o0][w0]         = fmaxf(acc0[0], 0.f);
        sH2[o0][w0 + 1]     = fmaxf(acc1[0], 0.f);
        sH2[o0 + 1][w0]     = fmaxf(acc0[1], 0.f);
        sH2[o0 + 1][w0 + 1] = fmaxf(acc1[1], 0.f);
    }
    __syncthreads();

    // ---- conv3: 64 -> 32, relu, scatter.  thread = (o = t&31,
    //      wh = t>>5 -> 2 w's). Per c: 1 global b32 + 1 LDS b64 + 2 FMA.
    {
        const int o = t & 31, w0 = 2 * (t >> 5);
        float acc0 = cb3[o], acc1 = acc0;
        #pragma unroll 8
        for (int c = 0; c < 64; ++c) {
            const float wv = cw3[c * 32 + o];
            const float2 xi = *(const float2*)&sH2[c][w0];
            acc0 += xi.x * wv;
            acc1 += xi.y * wv;
        }
        const int kbase = ((o * 8 + zi) * 8 + yi) * 15;
        fvecT[(size_t)(kbase + w0) * 8 + b] = fmaxf(acc0, 0.f);
        if (w0 + 1 < 15)
            fvecT[(size_t)(kbase + w0 + 1) * 8 + b] = fmaxf(acc1, 0.f);
    }
}

// ---------------------------------------------------------------------------
// K2: column-panel streamer (R11-exact, measured ~155 us ≈ stream floor).
// 64-thread blocks, KSPLIT=120 -> 1800 blocks (stream-count sweet spot).
// ---------------------------------------------------------------------------
__global__ __launch_bounds__(64) void k2_stream(
    const float* __restrict__ hw,
    const float* __restrict__ fvecT,
    const float* __restrict__ coord,
    float* __restrict__ partial)
{
    __shared__ float zpart[512];
    __shared__ float sF[KCH * 8];  // this k-chunk's fvec, all 8 batches (8 KB)
    const int t = threadIdx.x;     // 0..63
    const int kbase = blockIdx.y * KCH;

    #pragma unroll
    for (int r = 0; r < 8; ++r) zpart[t * 8 + r] = 0.f;
    {
        const float4* fsrc = (const float4*)(fvecT + (size_t)kbase * 8);
        float4* fdst = (float4*)sF;
        #pragma unroll
        for (int p = 0; p < 8; ++p) fdst[t + 64 * p] = fsrc[t + 64 * p];
    }
    __syncthreads();

    const int jw = blockIdx.x * 512;
    const int j0 = jw + 4 * t;

    float accA[8][4] = {}, accB[8][4] = {};
    const float* hp = hw + (size_t)kbase * NWCOL + j0;

    #pragma unroll 4
    for (int kk = 0; kk < KCH; ++kk) {
        const float4 hA = *(const float4*)hp;
        const float4 hB = *(const float4*)(hp + 256);
        hp += NWCOL;
        const float4 f0 = *(const float4*)&sF[kk * 8];      // broadcast
        const float4 f1 = *(const float4*)&sF[kk * 8 + 4];  // broadcast
        const float fv[8] = {f0.x, f0.y, f0.z, f0.w, f1.x, f1.y, f1.z, f1.w};
        #pragma unroll
        for (int b = 0; b < 8; ++b) {
            accA[b][0] += fv[b] * hA.x;
            accA[b][1] += fv[b] * hA.y;
            accA[b][2] += fv[b] * hA.z;
            accA[b][3] += fv[b] * hA.w;
            accB[b][0] += fv[b] * hB.x;
            accB[b][1] += fv[b] * hB.y;
            accB[b][2] += fv[b] * hB.z;
            accB[b][3] += fv[b] * hB.w;
        }
    }

    // fold z[b,f] for both col-quads (same output cols cq.., different f)
    const int fA = 8 * blockIdx.x + (t >> 4);
    const int fB = fA + 4;
    const int i3A = fA / 40, qA = fA - 40 * i3A;
    const int i3B = fB / 40, qB = fB - 40 * i3B;
    const float freqA = __expf((float)qA * LN1024_OVER_39);
    const float freqB = __expf((float)qB * LN1024_OVER_39);
    const int cq = 4 * (t & 15);

    #pragma unroll
    for (int b = 0; b < 8; ++b) {
        const float zvA = coord[b * 3 + i3A] * freqA;
        const float zvB = coord[b * 3 + i3B] * freqB;
        #pragma unroll
        for (int e = 0; e < 4; ++e)
            atomicAdd(&zpart[b * 64 + cq + e],
                      zvA * accA[b][e] + zvB * accB[b][e]);
    }
    __syncthreads();

    const int bid = blockIdx.x + 15 * blockIdx.y;
    float4* pp = (float4*)(partial + (size_t)bid * 512);
    pp[t]      = ((const float4*)zpart)[t];
    pp[t + 64] = ((const float4*)zpart)[t + 64];
}

// ---------------------------------------------------------------------------
// K2b: reduce partial[1800][512] -> z1[512]. 64 blocks x 256 threads.
// ---------------------------------------------------------------------------
__global__ __launch_bounds__(256) void k2b_reduce(
    const float* __restrict__ partial, float* __restrict__ z1)
{
    __shared__ float s[256];
    const int t = threadIdx.x;
    const int o = blockIdx.x * 8 + (t & 7);  // output element
    float sum = 0.f;
    for (int blk = t >> 3; blk < NBLK; blk += 32)
        sum += partial[(size_t)blk * 512 + o];
    s[t] = sum;
    __syncthreads();
    if (t < 8) {
        float tot = 0.f;
        #pragma unroll
        for (int i = 0; i < 32; ++i) tot += s[t + 8 * i];
        z1[blockIdx.x * 8 + t] = tot;
    }
}

// ---------------------------------------------------------------------------
// K3: hb-bias term + MLP tail, all weights LDS-staged (coalesced float4).
// One block, 512 threads = (b=8, c=64).
// ---------------------------------------------------------------------------
__global__ __launch_bounds__(512) void k3_tail(
    const float* __restrict__ z1acc, const float* __restrict__ coord,
    const float* __restrict__ hb,
    const float* __restrict__ w1, const float* __restrict__ b1,
    const float* __restrict__ w2, const float* __restrict__ b2,
    const float* __restrict__ wo, const float* __restrict__ bo,
    float* __restrict__ out)
{
    __shared__ float shb[7680];  // 30 KB
    __shared__ float sw1[4096];  // 16 KB
    __shared__ float sw2[4096];  // 16 KB
    __shared__ float swo[192];
    __shared__ float sz[8][64];
    __shared__ float s2[8][64];
    __shared__ float sfreq[40];
    __shared__ float sc[24];
    const int t = threadIdx.x;

    #pragma unroll
    for (int p = 0; p < 4; ++p) {
        const int idx = t + 512 * p;
        if (idx < 1920) ((float4*)shb)[idx] = ((const float4*)hb)[idx];
    }
    ((float4*)sw1)[t]       = ((const float4*)w1)[t];
    ((float4*)sw1)[t + 512] = ((const float4*)w1)[t + 512];
    ((float4*)sw2)[t]       = ((const float4*)w2)[t];
    ((float4*)sw2)[t + 512] = ((const float4*)w2)[t + 512];
    if (t < 48) ((float4*)swo)[t] = ((const float4*)wo)[t];
    if (t < 40) sfreq[t] = __expf((float)t * LN1024_OVER_39);
    if (t < 24) sc[t] = coord[t];
    __syncthreads();

    const int b = t >> 6, c = t & 63;

    float a = z1acc[t];
    #pragma unroll
    for (int i = 0; i < 3; ++i) {
        const float cv = sc[b * 3 + i];
        #pragma unroll 8
        for (int q = 0; q < 40; ++q)
            a += cv * sfreq[q] * shb[(i * 40 + q) * 64 + c];
    }
    sz[b][c] = a;  // no activation on modulated layer 0
    __syncthreads();

    float a1 = b1[c];
    #pragma unroll 8
    for (int cc = 0; cc < 64; ++cc) a1 += sz[b][cc] * sw1[cc * 64 + c];
    s2[b][c] = fmaxf(a1, 0.f);
    __syncthreads();

    float a2 = b2[c];
    #pragma unroll 8
    for (int cc = 0; cc < 64; ++cc) a2 += s2[b][cc] * sw2[cc * 64 + c];
    sz[b][c] = fmaxf(a2, 0.f);
    __syncthreads();

    if (t < 24) {
        const int bb = t / 3, i = t - bb * 3;
        float o = bo[i];
        #pragma unroll 8
        for (int cc = 0; cc < 64; ++cc) o += sz[bb][cc] * swo[cc * 3 + i];
        out[t] = o;
    }
}

// ---------------------------------------------------------------------------
extern "C" void kernel_launch(void* const* d_in, const int* in_sizes, int n_in,
                              void* d_out, int out_size, void* d_ws, size_t ws_size,
                              hipStream_t stream)
{
    const float* coord = (const float*)d_in[0];
    const float* feat0 = (const float*)d_in[1];
    const float* cw1 = (const float*)d_in[2];
    const float* cb1 = (const float*)d_in[3];
    const float* cw2 = (const float*)d_in[4];
    const float* cb2 = (const float*)d_in[5];
    const float* cw3 = (const float*)d_in[6];
    const float* cb3 = (const float*)d_in[7];
    const float* hw  = (const float*)d_in[8];
    const float* hb  = (const float*)d_in[9];
    const float* w1  = (const float*)d_in[10];
    const float* b1  = (const float*)d_in[11];
    const float* w2  = (const float*)d_in[12];
    const float* b2  = (const float*)d_in[13];
    const float* wo  = (const float*)d_in[14];
    const float* bo  = (const float*)d_in[15];
    float* out = (float*)d_out;

    float* fvecT   = (float*)d_ws;                  // 30720*8 floats = 983 KB
    float* partial = fvecT + (size_t)KTOT * 8;      // 1800*512 floats = 3.7 MB
    float* z1      = partial + (size_t)NBLK * 512;  // 512 floats

    k1_conv<<<dim3(8, 8, 8), 256, 0, stream>>>(feat0, cw1, cb1, cw2, cb2,
                                               cw3, cb3, fvecT);
    k2_stream<<<dim3(15, KSPLIT), 64, 0, stream>>>(hw, fvecT, coord, partial);
    k2b_reduce<<<64, 256, 0, stream>>>(partial, z1);
    k3_tail<<<1, 512, 0, stream>>>(z1, coord, hb, w1, b1, w2, b2, wo, bo, out);
}

// Round 13
// 229.392 us; speedup vs baseline: 1.0955x; 1.0955x over previous
//
#include <hip/hip_runtime.h>
#include <hip/hip_bf16.h>

#define DHW (16 * 16 * 30)   // 7680 voxels per channel
#define NWCOL 7680           // hw columns = 120 f * 64 c
#define KTOT 30720           // hw rows
#define KSPLIT 96
#define KCH (KTOT / KSPLIT)  // 320 rows per block
#define NBLK (15 * KSPLIT)   // 1440 K2 blocks (~5.6/CU)
// ln(1024)/39
#define LN1024_OVER_39 0.17773004629742187f

// ---------------------------------------------------------------------------
// K1 (R6-exact, measured ~31 us — best of 3 variants tried; LDS-staged
// weights beat global-weight reads at this occupancy, R12 post-mortem).
// One 512-thread block per (b, zi, yi).
// Writes fvecT[k][b], k = ((ch*8+zi)*8+yi)*15 + w   (torch flatten order)
// ---------------------------------------------------------------------------
__global__ __launch_bounds__(512) void k1_conv(
    const float* __restrict__ feat0,
    const float* __restrict__ cw1, const float* __restrict__ cb1,
    const float* __restrict__ cw2, const float* __restrict__ cb2,
    const float* __restrict__ cw3, const float* __restrict__ cb3,
    float* __restrict__ fvecT)
{
    const int yi = blockIdx.x;   // 0..7
    const int zi = blockIdx.y;   // 0..7
    const int b  = blockIdx.z;   // 0..7
    const int t  = threadIdx.x;  // 0..511

    __shared__ float sIn[256][16];  // 16 KB
    __shared__ float sW[8192];      // 32 KB staging (cw1 tiles / cw2 / cw3)
    __shared__ float sH1[128][16];  // 8 KB
    __shared__ float sH2[64][16];   // 4 KB

    // ---- load input voxels: feat0[b, c, 2zi, 2yi, 2w], w = 0..14 ----
    {
        const int w  = t & 15;
        const int cg = t >> 4;  // 0..31
        const float* base = feat0 + (size_t)b * 256 * DHW
                            + (2 * zi) * (16 * 30) + (2 * yi) * 30 + 2 * w;
        #pragma unroll
        for (int c0 = 0; c0 < 256; c0 += 32) {
            const int c = c0 + cg;
            sIn[c][w] = (w < 15) ? base[(size_t)c * DHW] : 0.f;
        }
    }

    // ---- conv1: 256 -> 128, relu.  o = t&127, wq = t>>7 (4 w's each) ----
    {
        const int o = t & 127, wq = t >> 7;
        const int w0 = 4 * wq;
        float acc[4];
        const float bv = cb1[o];
        #pragma unroll
        for (int i = 0; i < 4; ++i) acc[i] = bv;

        for (int c0 = 0; c0 < 256; c0 += 64) {
            // stage 64x128 tile of cw1 (contiguous 8192 floats)
            const float4* src = (const float4*)(cw1 + c0 * 128);
            float4* dst = (float4*)sW;
            #pragma unroll
            for (int p = 0; p < 4; ++p) dst[t + 512 * p] = src[t + 512 * p];
            __syncthreads();
            #pragma unroll 8
            for (int cc = 0; cc < 64; ++cc) {
                const float wv = sW[cc * 128 + o];
                const float4 xi = *(const float4*)&sIn[c0 + cc][w0];
                acc[0] += xi.x * wv;
                acc[1] += xi.y * wv;
                acc[2] += xi.z * wv;
                acc[3] += xi.w * wv;
            }
            __syncthreads();
        }
        #pragma unroll
        for (int i = 0; i < 4; ++i) sH1[o][w0 + i] = fmaxf(acc[i], 0.f);
    }
    __syncthreads();

    // ---- conv2: 128 -> 64, relu.  o = t&63, q = t>>6 (2 w's each) ----
    {
        const float4* src = (const float4*)cw2;
        float4* dst = (float4*)sW;
        #pragma unroll
        for (int p = 0; p < 4; ++p) dst[t + 512 * p] = src[t + 512 * p];
        __syncthreads();

        const int o = t & 63, q = t >> 6;
        const int w0 = 2 * q;
        float acc[2];
        const float bv = cb2[o];
        acc[0] = bv; acc[1] = bv;
        #pragma unroll 8
        for (int cc = 0; cc < 128; ++cc) {
            const float wv = sW[cc * 64 + o];
            const float2 xi = *(const float2*)&sH1[cc][w0];
            acc[0] += xi.x * wv;
            acc[1] += xi.y * wv;
        }
        sH2[o][w0]     = fmaxf(acc[0], 0.f);
        sH2[o][w0 + 1] = fmaxf(acc[1], 0.f);
    }
    __syncthreads();

    // ---- conv3: 64 -> 32, relu, scatter.  o = t&31, w = t>>5 ----
    {
        ((float4*)sW)[t] = ((const float4*)cw3)[t];
        __syncthreads();

        const int o = t & 31, w = t >> 5;
        float acc = cb3[o];
        #pragma unroll 8
        for (int cc = 0; cc < 64; ++cc)
            acc += sH2[cc][w] * sW[cc * 32 + o];
        if (w < 15) {
            const int k = ((o * 8 + zi) * 8 + yi) * 15 + w;
            fvecT[(size_t)k * 8 + b] = fmaxf(acc, 0.f);
        }
    }
}

// ---------------------------------------------------------------------------
// K2: column-panel streamer, 64-thread blocks (R11 inner loop EXACTLY);
// only change: KSPLIT 120->96 (KCH=320) -> 1440 blocks, testing the
// stream-count curve one step further. sF = 10 KB LDS.
// ---------------------------------------------------------------------------
__global__ __launch_bounds__(64) void k2_stream(
    const float* __restrict__ hw,
    const float* __restrict__ fvecT,
    const float* __restrict__ coord,
    float* __restrict__ partial)
{
    __shared__ float zpart[512];
    __shared__ float sF[KCH * 8];  // this k-chunk's fvec, all 8 batches (10 KB)
    const int t = threadIdx.x;     // 0..63
    const int kbase = blockIdx.y * KCH;

    #pragma unroll
    for (int r = 0; r < 8; ++r) zpart[t * 8 + r] = 0.f;
    {
        const float4* fsrc = (const float4*)(fvecT + (size_t)kbase * 8);
        float4* fdst = (float4*)sF;
        #pragma unroll
        for (int p = 0; p < 10; ++p) fdst[t + 64 * p] = fsrc[t + 64 * p];
    }
    __syncthreads();

    const int jw = blockIdx.x * 512;
    const int j0 = jw + 4 * t;

    float accA[8][4] = {}, accB[8][4] = {};
    const float* hp = hw + (size_t)kbase * NWCOL + j0;

    #pragma unroll 4
    for (int kk = 0; kk < KCH; ++kk) {
        const float4 hA = *(const float4*)hp;
        const float4 hB = *(const float4*)(hp + 256);
        hp += NWCOL;
        const float4 f0 = *(const float4*)&sF[kk * 8];      // broadcast
        const float4 f1 = *(const float4*)&sF[kk * 8 + 4];  // broadcast
        const float fv[8] = {f0.x, f0.y, f0.z, f0.w, f1.x, f1.y, f1.z, f1.w};
        #pragma unroll
        for (int b = 0; b < 8; ++b) {
            accA[b][0] += fv[b] * hA.x;
            accA[b][1] += fv[b] * hA.y;
            accA[b][2] += fv[b] * hA.z;
            accA[b][3] += fv[b] * hA.w;
            accB[b][0] += fv[b] * hB.x;
            accB[b][1] += fv[b] * hB.y;
            accB[b][2] += fv[b] * hB.z;
            accB[b][3] += fv[b] * hB.w;
        }
    }

    // fold z[b,f] for both col-quads (same output cols cq.., different f)
    const int fA = 8 * blockIdx.x + (t >> 4);
    const int fB = fA + 4;
    const int i3A = fA / 40, qA = fA - 40 * i3A;
    const int i3B = fB / 40, qB = fB - 40 * i3B;
    const float freqA = __expf((float)qA * LN1024_OVER_39);
    const float freqB = __expf((float)qB * LN1024_OVER_39);
    const int cq = 4 * (t & 15);

    #pragma unroll
    for (int b = 0; b < 8; ++b) {
        const float zvA = coord[b * 3 + i3A] * freqA;
        const float zvB = coord[b * 3 + i3B] * freqB;
        #pragma unroll
        for (int e = 0; e < 4; ++e)
            atomicAdd(&zpart[b * 64 + cq + e],
                      zvA * accA[b][e] + zvB * accB[b][e]);
    }
    __syncthreads();

    const int bid = blockIdx.x + 15 * blockIdx.y;
    float4* pp = (float4*)(partial + (size_t)bid * 512);
    pp[t]      = ((const float4*)zpart)[t];
    pp[t + 64] = ((const float4*)zpart)[t + 64];
}

// ---------------------------------------------------------------------------
// K2b: reduce partial[1440][512] -> z1[512]. 64 blocks x 256 threads.
// ---------------------------------------------------------------------------
__global__ __launch_bounds__(256) void k2b_reduce(
    const float* __restrict__ partial, float* __restrict__ z1)
{
    __shared__ float s[256];
    const int t = threadIdx.x;
    const int o = blockIdx.x * 8 + (t & 7);  // output element
    float sum = 0.f;
    for (int blk = t >> 3; blk < NBLK; blk += 32)
        sum += partial[(size_t)blk * 512 + o];
    s[t] = sum;
    __syncthreads();
    if (t < 8) {
        float tot = 0.f;
        #pragma unroll
        for (int i = 0; i < 32; ++i) tot += s[t + 8 * i];
        z1[blockIdx.x * 8 + t] = tot;
    }
}

// ---------------------------------------------------------------------------
// K3: hb-bias term + MLP tail, all weights LDS-staged (coalesced float4).
// One block, 512 threads = (b=8, c=64).
// ---------------------------------------------------------------------------
__global__ __launch_bounds__(512) void k3_tail(
    const float* __restrict__ z1acc, const float* __restrict__ coord,
    const float* __restrict__ hb,
    const float* __restrict__ w1, const float* __restrict__ b1,
    const float* __restrict__ w2, const float* __restrict__ b2,
    const float* __restrict__ wo, const float* __restrict__ bo,
    float* __restrict__ out)
{
    __shared__ float shb[7680];  // 30 KB
    __shared__ float sw1[4096];  // 16 KB
    __shared__ float sw2[4096];  // 16 KB
    __shared__ float swo[192];
    __shared__ float sz[8][64];
    __shared__ float s2[8][64];
    __shared__ float sfreq[40];
    __shared__ float sc[24];
    const int t = threadIdx.x;

    #pragma unroll
    for (int p = 0; p < 4; ++p) {
        const int idx = t + 512 * p;
        if (idx < 1920) ((float4*)shb)[idx] = ((const float4*)hb)[idx];
    }
    ((float4*)sw1)[t]       = ((const float4*)w1)[t];
    ((float4*)sw1)[t + 512] = ((const float4*)w1)[t + 512];
    ((float4*)sw2)[t]       = ((const float4*)w2)[t];
    ((float4*)sw2)[t + 512] = ((const float4*)w2)[t + 512];
    if (t < 48) ((float4*)swo)[t] = ((const float4*)wo)[t];
    if (t < 40) sfreq[t] = __expf((float)t * LN1024_OVER_39);
    if (t < 24) sc[t] = coord[t];
    __syncthreads();

    const int b = t >> 6, c = t & 63;

    float a = z1acc[t];
    #pragma unroll
    for (int i = 0; i < 3; ++i) {
        const float cv = sc[b * 3 + i];
        #pragma unroll 8
        for (int q = 0; q < 40; ++q)
            a += cv * sfreq[q] * shb[(i * 40 + q) * 64 + c];
    }
    sz[b][c] = a;  // no activation on modulated layer 0
    __syncthreads();

    float a1 = b1[c];
    #pragma unroll 8
    for (int cc = 0; cc < 64; ++cc) a1 += sz[b][cc] * sw1[cc * 64 + c];
    s2[b][c] = fmaxf(a1, 0.f);
    __syncthreads();

    float a2 = b2[c];
    #pragma unroll 8
    for (int cc = 0; cc < 64; ++cc) a2 += s2[b][cc] * sw2[cc * 64 + c];
    sz[b][c] = fmaxf(a2, 0.f);
    __syncthreads();

    if (t < 24) {
        const int bb = t / 3, i = t - bb * 3;
        float o = bo[i];
        #pragma unroll 8
        for (int cc = 0; cc < 64; ++cc) o += sz[bb][cc] * swo[cc * 3 + i];
        out[t] = o;
    }
}

// ---------------------------------------------------------------------------
extern "C" void kernel_launch(void* const* d_in, const int* in_sizes, int n_in,
                              void* d_out, int out_size, void* d_ws, size_t ws_size,
                              hipStream_t stream)
{
    const float* coord = (const float*)d_in[0];
    const float* feat0 = (const float*)d_in[1];
    const float* cw1 = (const float*)d_in[2];
    const float* cb1 = (const float*)d_in[3];
    const float* cw2 = (const float*)d_in[4];
    const float* cb2 = (const float*)d_in[5];
    const float* cw3 = (const float*)d_in[6];
    const float* cb3 = (const float*)d_in[7];
    const float* hw  = (const float*)d_in[8];
    const float* hb  = (const float*)d_in[9];
    const float* w1  = (const float*)d_in[10];
    const float* b1  = (const float*)d_in[11];
    const float* w2  = (const float*)d_in[12];
    const float* b2  = (const float*)d_in[13];
    const float* wo  = (const float*)d_in[14];
    const float* bo  = (const float*)d_in[15];
    float* out = (float*)d_out;

    float* fvecT   = (float*)d_ws;                  // 30720*8 floats = 983 KB
    float* partial = fvecT + (size_t)KTOT * 8;      // 1440*512 floats = 2.95 MB
    float* z1      = partial + (size_t)NBLK * 512;  // 512 floats

    k1_conv<<<dim3(8, 8, 8), 512, 0, stream>>>(feat0, cw1, cb1, cw2, cb2,
                                               cw3, cb3, fvecT);
    k2_stream<<<dim3(15, KSPLIT), 64, 0, stream>>>(hw, fvecT, coord, partial);
    k2b_reduce<<<64, 256, 0, stream>>>(partial, z1);
    k3_tail<<<1, 512, 0, stream>>>(z1, coord, hb, w1, b1, w2, b2, wo, bo, out);
}

// Round 14
// 220.694 us; speedup vs baseline: 1.1387x; 1.0394x over previous
//
#include <hip/hip_runtime.h>
#include <hip/hip_bf16.h>

#define DHW (16 * 16 * 30)   // 7680 voxels per channel
#define NWCOL 7680           // hw columns = 120 f * 64 c
#define KTOT 30720           // hw rows
#define KSPLIT 96
#define KCH (KTOT / KSPLIT)  // 320 rows per block
#define NBLK (15 * KSPLIT)   // 1440 K2 blocks (~5.6/CU)
// ln(1024)/39
#define LN1024_OVER_39 0.17773004629742187f

// ---------------------------------------------------------------------------
// K1 v4: conv chain, register-tiled to cut LDS issue 4x vs R6 (which measured
// 31 us and was LDS-issue-bound: 2 LDS instrs / 4 FMA). Threads tile
// 4o x 4w (conv1), c-split 4 ways across cs = t>>7 over each staged tile,
// LDS partial reduction per layer. 2 LDS instrs / 16 FMA in conv1.
// One 512-thread block per (b, zi, yi); 60 KB LDS -> 2 blocks/CU (as R6).
// Writes fvecT[k][b], k = ((ch*8+zi)*8+yi)*15 + w   (torch flatten order)
// ---------------------------------------------------------------------------
__global__ __launch_bounds__(512) void k1_conv(
    const float* __restrict__ feat0,
    const float* __restrict__ cw1, const float* __restrict__ cb1,
    const float* __restrict__ cw2, const float* __restrict__ cb2,
    const float* __restrict__ cw3, const float* __restrict__ cb3,
    float* __restrict__ fvecT)
{
    const int yi = blockIdx.x;   // 0..7
    const int zi = blockIdx.y;   // 0..7
    const int b  = blockIdx.z;   // 0..7
    const int t  = threadIdx.x;  // 0..511

    __shared__ float sIn[256][16];  // 16 KB
    __shared__ float sW[8192];      // 32 KB: weight tiles / partial sums
    __shared__ float sH1[128][16];  // 8 KB
    __shared__ float sH2[64][16];   // 4 KB

    const int og = t & 31;          // conv1/2 o-group
    const int wg = (t >> 5) & 3;    // conv1/2 w-group
    const int cs = t >> 7;          // c-split id 0..3
    const int u  = t & 127;         // (og,wg) unit id, shared across cs

    // ---- load input voxels: feat0[b, c, 2zi, 2yi, 2w], w = 0..14 ----
    {
        const int w  = t & 15;
        const int cg = t >> 4;  // 0..31
        const float* base = feat0 + (size_t)b * 256 * DHW
                            + (2 * zi) * (16 * 30) + (2 * yi) * 30 + 2 * w;
        #pragma unroll
        for (int c0 = 0; c0 < 256; c0 += 32) {
            const int c = c0 + cg;
            sIn[c][w] = (w < 15) ? base[(size_t)c * DHW] : 0.f;
        }
    }
    // (first staging sync below covers sIn)

    // ================= conv1: 256 -> 128, relu =================
    {
        const int o0 = 4 * og, w0 = 4 * wg;
        float acc[4][4] = {};
        for (int c0 = 0; c0 < 256; c0 += 64) {
            // stage 64x128 tile of cw1
            const float4* src = (const float4*)(cw1 + c0 * 128);
            float4* dst = (float4*)sW;
            #pragma unroll
            for (int p = 0; p < 4; ++p) dst[t + 512 * p] = src[t + 512 * p];
            __syncthreads();
            #pragma unroll 4
            for (int j = 0; j < 16; ++j) {
                const int cc = 16 * cs + j;
                const float4 wv = *(const float4*)&sW[cc * 128 + o0];
                const float4 xi = *(const float4*)&sIn[c0 + cc][w0];
                acc[0][0] += xi.x * wv.x; acc[0][1] += xi.y * wv.x;
                acc[0][2] += xi.z * wv.x; acc[0][3] += xi.w * wv.x;
                acc[1][0] += xi.x * wv.y; acc[1][1] += xi.y * wv.y;
                acc[1][2] += xi.z * wv.y; acc[1][3] += xi.w * wv.y;
                acc[2][0] += xi.x * wv.z; acc[2][1] += xi.y * wv.z;
                acc[2][2] += xi.z * wv.z; acc[2][3] += xi.w * wv.z;
                acc[3][0] += xi.x * wv.w; acc[3][1] += xi.y * wv.w;
                acc[3][2] += xi.z * wv.w; acc[3][3] += xi.w * wv.w;
            }
            __syncthreads();
        }
        // cs>0 park partials in sW (free: last sync passed)
        if (cs > 0) {
            float4* pw = (float4*)&sW[(cs - 1) * 2048 + u * 16];
            #pragma unroll
            for (int j = 0; j < 4; ++j) pw[j] = *(const float4*)&acc[j][0];
        }
        __syncthreads();
        if (cs == 0) {
            #pragma unroll
            for (int s = 0; s < 3; ++s) {
                const float4* pr = (const float4*)&sW[s * 2048 + u * 16];
                #pragma unroll
                for (int j = 0; j < 4; ++j) {
                    const float4 v = pr[j];
                    acc[j][0] += v.x; acc[j][1] += v.y;
                    acc[j][2] += v.z; acc[j][3] += v.w;
                }
            }
            const float4 bv = *(const float4*)&cb1[o0];
            const float bb[4] = {bv.x, bv.y, bv.z, bv.w};
            #pragma unroll
            for (int j = 0; j < 4; ++j) {
                float4 r;
                r.x = fmaxf(acc[j][0] + bb[j], 0.f);
                r.y = fmaxf(acc[j][1] + bb[j], 0.f);
                r.z = fmaxf(acc[j][2] + bb[j], 0.f);
                r.w = fmaxf(acc[j][3] + bb[j], 0.f);
                *(float4*)&sH1[o0 + j][w0] = r;
            }
        }
        __syncthreads();
    }

    // ================= conv2: 128 -> 64, relu =================
    {
        const int o0 = 2 * og, w0 = 4 * wg;
        // stage cw2 fully (128x64 = 8192 floats)
        const float4* src = (const float4*)cw2;
        float4* dst = (float4*)sW;
        #pragma unroll
        for (int p = 0; p < 4; ++p) dst[t + 512 * p] = src[t + 512 * p];
        __syncthreads();

        float acc[2][4] = {};
        #pragma unroll 4
        for (int j = 0; j < 32; ++j) {
            const int cc = 32 * cs + j;
            const float2 wv = *(const float2*)&sW[cc * 64 + o0];
            const float4 xi = *(const float4*)&sH1[cc][w0];
            acc[0][0] += xi.x * wv.x; acc[0][1] += xi.y * wv.x;
            acc[0][2] += xi.z * wv.x; acc[0][3] += xi.w * wv.x;
            acc[1][0] += xi.x * wv.y; acc[1][1] += xi.y * wv.y;
            acc[1][2] += xi.z * wv.y; acc[1][3] += xi.w * wv.y;
        }
        __syncthreads();  // cw2 reads done -> sW reusable

        if (cs > 0) {
            float4* pw = (float4*)&sW[(cs - 1) * 1024 + u * 8];
            pw[0] = *(const float4*)&acc[0][0];
            pw[1] = *(const float4*)&acc[1][0];
        }
        // stage cw3 (2048 floats) into sW[4096..6143] — disjoint region
        ((float4*)&sW[4096])[t] = ((const float4*)cw3)[t];
        __syncthreads();

        if (cs == 0) {
            #pragma unroll
            for (int s = 0; s < 3; ++s) {
                const float4* pr = (const float4*)&sW[s * 1024 + u * 8];
                const float4 v0 = pr[0], v1 = pr[1];
                acc[0][0] += v0.x; acc[0][1] += v0.y;
                acc[0][2] += v0.z; acc[0][3] += v0.w;
                acc[1][0] += v1.x; acc[1][1] += v1.y;
                acc[1][2] += v1.z; acc[1][3] += v1.w;
            }
            const float2 bv = *(const float2*)&cb2[o0];
            float4 r0, r1;
            r0.x = fmaxf(acc[0][0] + bv.x, 0.f);
            r0.y = fmaxf(acc[0][1] + bv.x, 0.f);
            r0.z = fmaxf(acc[0][2] + bv.x, 0.f);
            r0.w = fmaxf(acc[0][3] + bv.x, 0.f);
            r1.x = fmaxf(acc[1][0] + bv.y, 0.f);
            r1.y = fmaxf(acc[1][1] + bv.y, 0.f);
            r1.z = fmaxf(acc[1][2] + bv.y, 0.f);
            r1.w = fmaxf(acc[1][3] + bv.y, 0.f);
            *(float4*)&sH2[o0][w0]     = r0;
            *(float4*)&sH2[o0 + 1][w0] = r1;
        }
        __syncthreads();
    }

    // ================= conv3: 64 -> 32, relu, scatter =================
    {
        const int og3 = t & 15, wg3 = (t >> 4) & 7, cs3 = t >> 7;
        const int o0 = 2 * og3, w0 = 2 * wg3;
        const int u3 = t & 127;
        float acc[2][2] = {};
        #pragma unroll 4
        for (int j = 0; j < 16; ++j) {
            const int cc = 16 * cs3 + j;
            const float2 wv = *(const float2*)&sW[4096 + cc * 32 + o0];
            const float2 xi = *(const float2*)&sH2[cc][w0];
            acc[0][0] += xi.x * wv.x; acc[0][1] += xi.y * wv.x;
            acc[1][0] += xi.x * wv.y; acc[1][1] += xi.y * wv.y;
        }
        // partial region sW[0..1535] is idle since conv2 epilogue sync
        if (cs3 > 0) {
            float4 v;
            v.x = acc[0][0]; v.y = acc[0][1]; v.z = acc[1][0]; v.w = acc[1][1];
            *(float4*)&sW[(cs3 - 1) * 512 + u3 * 4] = v;
        }
        __syncthreads();
        if (cs3 == 0) {
            #pragma unroll
            for (int s = 0; s < 3; ++s) {
                const float4 v = *(const float4*)&sW[s * 512 + u3 * 4];
                acc[0][0] += v.x; acc[0][1] += v.y;
                acc[1][0] += v.z; acc[1][1] += v.w;
            }
            const float2 bv = *(const float2*)&cb3[o0];
            #pragma unroll
            for (int oj = 0; oj < 2; ++oj) {
                const int kbase = (((o0 + oj) * 8 + zi) * 8 + yi) * 15;
                const float bj = oj ? bv.y : bv.x;
                #pragma unroll
                for (int wj = 0; wj < 2; ++wj) {
                    const int w = w0 + wj;
                    if (w < 15)
                        fvecT[(size_t)(kbase + w) * 8 + b] =
                            fmaxf(acc[oj][wj] + bj, 0.f);
                }
            }
        }
    }
}

// ---------------------------------------------------------------------------
// K2: column-panel streamer (R13-exact, measured ~144 us). 64-thread blocks,
// KSPLIT=96 -> 1440 blocks. sF = 10 KB LDS.
// ---------------------------------------------------------------------------
__global__ __launch_bounds__(64) void k2_stream(
    const float* __restrict__ hw,
    const float* __restrict__ fvecT,
    const float* __restrict__ coord,
    float* __restrict__ partial)
{
    __shared__ float zpart[512];
    __shared__ float sF[KCH * 8];  // this k-chunk's fvec, all 8 batches (10 KB)
    const int t = threadIdx.x;     // 0..63
    const int kbase = blockIdx.y * KCH;

    #pragma unroll
    for (int r = 0; r < 8; ++r) zpart[t * 8 + r] = 0.f;
    {
        const float4* fsrc = (const float4*)(fvecT + (size_t)kbase * 8);
        float4* fdst = (float4*)sF;
        #pragma unroll
        for (int p = 0; p < 10; ++p) fdst[t + 64 * p] = fsrc[t + 64 * p];
    }
    __syncthreads();

    const int jw = blockIdx.x * 512;
    const int j0 = jw + 4 * t;

    float accA[8][4] = {}, accB[8][4] = {};
    const float* hp = hw + (size_t)kbase * NWCOL + j0;

    #pragma unroll 4
    for (int kk = 0; kk < KCH; ++kk) {
        const float4 hA = *(const float4*)hp;
        const float4 hB = *(const float4*)(hp + 256);
        hp += NWCOL;
        const float4 f0 = *(const float4*)&sF[kk * 8];      // broadcast
        const float4 f1 = *(const float4*)&sF[kk * 8 + 4];  // broadcast
        const float fv[8] = {f0.x, f0.y, f0.z, f0.w, f1.x, f1.y, f1.z, f1.w};
        #pragma unroll
        for (int b = 0; b < 8; ++b) {
            accA[b][0] += fv[b] * hA.x;
            accA[b][1] += fv[b] * hA.y;
            accA[b][2] += fv[b] * hA.z;
            accA[b][3] += fv[b] * hA.w;
            accB[b][0] += fv[b] * hB.x;
            accB[b][1] += fv[b] * hB.y;
            accB[b][2] += fv[b] * hB.z;
            accB[b][3] += fv[b] * hB.w;
        }
    }

    // fold z[b,f] for both col-quads (same output cols cq.., different f)
    const int fA = 8 * blockIdx.x + (t >> 4);
    const int fB = fA + 4;
    const int i3A = fA / 40, qA = fA - 40 * i3A;
    const int i3B = fB / 40, qB = fB - 40 * i3B;
    const float freqA = __expf((float)qA * LN1024_OVER_39);
    const float freqB = __expf((float)qB * LN1024_OVER_39);
    const int cq = 4 * (t & 15);

    #pragma unroll
    for (int b = 0; b < 8; ++b) {
        const float zvA = coord[b * 3 + i3A] * freqA;
        const float zvB = coord[b * 3 + i3B] * freqB;
        #pragma unroll
        for (int e = 0; e < 4; ++e)
            atomicAdd(&zpart[b * 64 + cq + e],
                      zvA * accA[b][e] + zvB * accB[b][e]);
    }
    __syncthreads();

    const int bid = blockIdx.x + 15 * blockIdx.y;
    float4* pp = (float4*)(partial + (size_t)bid * 512);
    pp[t]      = ((const float4*)zpart)[t];
    pp[t + 64] = ((const float4*)zpart)[t + 64];
}

// ---------------------------------------------------------------------------
// K2b: reduce partial[1440][512] -> z1[512]. 64 blocks x 256 threads.
// ---------------------------------------------------------------------------
__global__ __launch_bounds__(256) void k2b_reduce(
    const float* __restrict__ partial, float* __restrict__ z1)
{
    __shared__ float s[256];
    const int t = threadIdx.x;
    const int o = blockIdx.x * 8 + (t & 7);  // output element
    float sum = 0.f;
    for (int blk = t >> 3; blk < NBLK; blk += 32)
        sum += partial[(size_t)blk * 512 + o];
    s[t] = sum;
    __syncthreads();
    if (t < 8) {
        float tot = 0.f;
        #pragma unroll
        for (int i = 0; i < 32; ++i) tot += s[t + 8 * i];
        z1[blockIdx.x * 8 + t] = tot;
    }
}

// ---------------------------------------------------------------------------
// K3: hb-bias term + MLP tail, all weights LDS-staged (coalesced float4).
// One block, 512 threads = (b=8, c=64).
// ---------------------------------------------------------------------------
__global__ __launch_bounds__(512) void k3_tail(
    const float* __restrict__ z1acc, const float* __restrict__ coord,
    const float* __restrict__ hb,
    const float* __restrict__ w1, const float* __restrict__ b1,
    const float* __restrict__ w2, const float* __restrict__ b2,
    const float* __restrict__ wo, const float* __restrict__ bo,
    float* __restrict__ out)
{
    __shared__ float shb[7680];  // 30 KB
    __shared__ float sw1[4096];  // 16 KB
    __shared__ float sw2[4096];  // 16 KB
    __shared__ float swo[192];
    __shared__ float sz[8][64];
    __shared__ float s2[8][64];
    __shared__ float sfreq[40];
    __shared__ float sc[24];
    const int t = threadIdx.x;

    #pragma unroll
    for (int p = 0; p < 4; ++p) {
        const int idx = t + 512 * p;
        if (idx < 1920) ((float4*)shb)[idx] = ((const float4*)hb)[idx];
    }
    ((float4*)sw1)[t]       = ((const float4*)w1)[t];
    ((float4*)sw1)[t + 512] = ((const float4*)w1)[t + 512];
    ((float4*)sw2)[t]       = ((const float4*)w2)[t];
    ((float4*)sw2)[t + 512] = ((const float4*)w2)[t + 512];
    if (t < 48) ((float4*)swo)[t] = ((const float4*)wo)[t];
    if (t < 40) sfreq[t] = __expf((float)t * LN1024_OVER_39);
    if (t < 24) sc[t] = coord[t];
    __syncthreads();

    const int b = t >> 6, c = t & 63;

    float a = z1acc[t];
    #pragma unroll
    for (int i = 0; i < 3; ++i) {
        const float cv = sc[b * 3 + i];
        #pragma unroll 8
        for (int q = 0; q < 40; ++q)
            a += cv * sfreq[q] * shb[(i * 40 + q) * 64 + c];
    }
    sz[b][c] = a;  // no activation on modulated layer 0
    __syncthreads();

    float a1 = b1[c];
    #pragma unroll 8
    for (int cc = 0; cc < 64; ++cc) a1 += sz[b][cc] * sw1[cc * 64 + c];
    s2[b][c] = fmaxf(a1, 0.f);
    __syncthreads();

    float a2 = b2[c];
    #pragma unroll 8
    for (int cc = 0; cc < 64; ++cc) a2 += s2[b][cc] * sw2[cc * 64 + c];
    sz[b][c] = fmaxf(a2, 0.f);
    __syncthreads();

    if (t < 24) {
        const int bb = t / 3, i = t - bb * 3;
        float o = bo[i];
        #pragma unroll 8
        for (int cc = 0; cc < 64; ++cc) o += sz[bb][cc] * swo[cc * 3 + i];
        out[t] = o;
    }
}

// ---------------------------------------------------------------------------
extern "C" void kernel_launch(void* const* d_in, const int* in_sizes, int n_in,
                              void* d_out, int out_size, void* d_ws, size_t ws_size,
                              hipStream_t stream)
{
    const float* coord = (const float*)d_in[0];
    const float* feat0 = (const float*)d_in[1];
    const float* cw1 = (const float*)d_in[2];
    const float* cb1 = (const float*)d_in[3];
    const float* cw2 = (const float*)d_in[4];
    const float* cb2 = (const float*)d_in[5];
    const float* cw3 = (const float*)d_in[6];
    const float* cb3 = (const float*)d_in[7];
    const float* hw  = (const float*)d_in[8];
    const float* hb  = (const float*)d_in[9];
    const float* w1  = (const float*)d_in[10];
    const float* b1  = (const float*)d_in[11];
    const float* w2  = (const float*)d_in[12];
    const float* b2  = (const float*)d_in[13];
    const float* wo  = (const float*)d_in[14];
    const float* bo  = (const float*)d_in[15];
    float* out = (float*)d_out;

    float* fvecT   = (float*)d_ws;                  // 30720*8 floats = 983 KB
    float* partial = fvecT + (size_t)KTOT * 8;      // 1440*512 floats = 2.95 MB
    float* z1      = partial + (size_t)NBLK * 512;  // 512 floats

    k1_conv<<<dim3(8, 8, 8), 512, 0, stream>>>(feat0, cw1, cb1, cw2, cb2,
                                               cw3, cb3, fvecT);
    k2_stream<<<dim3(15, KSPLIT), 64, 0, stream>>>(hw, fvecT, coord, partial);
    k2b_reduce<<<64, 256, 0, stream>>>(partial, z1);
    k3_tail<<<1, 512, 0, stream>>>(z1, coord, hb, w1, b1, w2, b2, wo, bo, out);
}